// Round 12
// baseline (2575.439 us; speedup 1.0000x reference)
//
#include <hip/hip_runtime.h>
#include <hip/hip_bf16.h>
#include <stdint.h>

typedef short bf16x8 __attribute__((ext_vector_type(8)));
typedef float f32x4  __attribute__((ext_vector_type(4)));

__device__ __forceinline__ ushort f2b(float f) {
  __hip_bfloat16 t = __float2bfloat16(f);
  return *reinterpret_cast<ushort*>(&t);
}
__device__ __forceinline__ bf16x8 pack8(float4 a, float4 b) {
  bf16x8 r;
  r[0]=(short)f2b(a.x); r[1]=(short)f2b(a.y); r[2]=(short)f2b(a.z); r[3]=(short)f2b(a.w);
  r[4]=(short)f2b(b.x); r[5]=(short)f2b(b.y); r[6]=(short)f2b(b.z); r[7]=(short)f2b(b.w);
  return r;
}

// Raw barrier: LDS-visibility only; global prefetch loads stay in flight (T4).
__device__ __forceinline__ void lds_barrier() {
  asm volatile("s_waitcnt lgkmcnt(0)" ::: "memory");
  __builtin_amdgcn_sched_barrier(0);
  __builtin_amdgcn_s_barrier();
  __builtin_amdgcn_sched_barrier(0);
}

#define BCAP 98304   // per-bucket record capacity (mean 75k, sd ~256 -> never overflows)

// ---------------- Kernel 1: W1 repack (blocks >=256)  +  edge bucketing (blocks <256) -------
// gmeta: [0..7] bucket counts, [8] ovf count, [9..16] bucket cursors, [17] ovf cursor.
__global__ void repack_bucket(const float* __restrict__ W1, int4* __restrict__ blob,
                              const int* __restrict__ src, const int* __restrict__ dst,
                              int4* __restrict__ bkt, int4* __restrict__ ovf,
                              int* __restrict__ gmeta, int E, unsigned Mdiv) {
  const int bid = blockIdx.x;
  const int t0  = threadIdx.x;
  if (bid >= 256) {
    const int tid = (bid - 256) * 256 + t0;           // 0..4095
    const int l15  = tid & 15;
    const int lg   = (tid >> 4) & 3;
    const int kk   = (tid >> 6) & 3;
    const int nt   = (tid >> 8) & 7;
    const int half = (tid >> 11) & 1;
    const float* wp = W1 + (size_t)(nt * 16 + l15) * 256 + half * 128 + kk * 32 + lg * 8;
    const float4 fa = *(const float4*)wp;
    const float4 fb = *(const float4*)(wp + 4);
    bf16x8 r = pack8(fa, fb);
    blob[tid] = *reinterpret_cast<int4*>(&r);
    return;
  }
  // ---- bucket path: histogram + reserve + scatter {s,d,e,0} records ----
  __shared__ int lh[8], lh2[8], lbs[8];
  const int C  = (E + 255) >> 8;
  const int e0 = bid * C;
  const int e1 = (e0 + C) < E ? (e0 + C) : E;
  if (t0 < 8) { lh[t0] = 0; lh2[t0] = 0; }
  __syncthreads();
  for (int e = e0 + t0; e < e1; e += 256) {
    const unsigned s = (unsigned)src[e];
    int sh = (int)(((unsigned long long)s * Mdiv) >> 34);
    sh = sh > 7 ? 7 : sh;
    atomicAdd(&lh[sh], 1);
  }
  __syncthreads();
  if (t0 < 8) lbs[t0] = atomicAdd(&gmeta[t0], lh[t0]);
  __syncthreads();
  for (int e = e0 + t0; e < e1; e += 256) {
    const int s = src[e];
    const int d = dst[e];
    int sh = (int)(((unsigned long long)(unsigned)s * Mdiv) >> 34);
    sh = sh > 7 ? 7 : sh;
    const int r = atomicAdd(&lh2[sh], 1);
    const int slot = lbs[sh] + r;
    const int4 rec = make_int4(s, d, e, 0);
    if (slot < BCAP) bkt[(size_t)sh * BCAP + slot] = rec;
    else             ovf[atomicAdd(&gmeta[8], 1)] = rec;
  }
}

// ---------------- Kernel 2: node u/v -> biased uint8 + per-half scales (round-8 exact) ------
__global__ __launch_bounds__(256, 3) void node_uv(
    const float* __restrict__ h, const int4* __restrict__ blob,
    const float* __restrict__ b1,
    uint8_t* __restrict__ u8, uint8_t* __restrict__ v8,
    float* __restrict__ su, float* __restrict__ sv,   // [Nn][2]
    int Nn, int NT, int nb, int niter)
{
  __shared__ ushort As[2][2048];

  const int t0   = threadIdx.x;
  const int w    = t0 >> 6;
  const int l    = t0 & 63;
  const int l15  = l & 15;
  const int lg   = l >> 4;
  const int half = w >> 1;
  const int hw   = w & 1;

  bf16x8 bfrag[4][4];
#pragma unroll
  for (int ntl = 0; ntl < 4; ++ntl)
#pragma unroll
    for (int kk = 0; kk < 4; ++kk) {
      int4 x = blob[((half * 8 + hw * 4 + ntl) * 4 + kk) * 64 + l];
      bfrag[ntl][kk] = *reinterpret_cast<bf16x8*>(&x);
    }

  float b1r[4];
#pragma unroll
  for (int ntl = 0; ntl < 4; ++ntl)
    b1r[ntl] = half ? 0.f : b1[hw * 64 + ntl * 16 + l15];

  uint8_t* __restrict__ outp = half ? v8 : u8;
  float*   __restrict__ outs = half ? sv : su;

  const float4* h4 = (const float4*)h;

#define LOADT(T, g)                                            \
  {                                                            \
    const size_t hb = (size_t)(T) * 512;                       \
    _Pragma("unroll")                                          \
    for (int k = 0; k < 2; ++k) {                              \
      const int i = k * 256 + t0;                              \
      const int gr = (T) * 16 + (i >> 5);                      \
      (g)[k] = h4[gr < Nn ? hb + i : 0];                       \
    }                                                          \
  }

#define STORET(b, g)                                           \
  {                                                            \
    _Pragma("unroll")                                          \
    for (int k = 0; k < 2; ++k) {                              \
      const int i = k * 256 + t0, row = i >> 5, c = i & 31;    \
      ushort4 o;                                               \
      o.x = f2b((g)[k].x); o.y = f2b((g)[k].y);                \
      o.z = f2b((g)[k].z); o.w = f2b((g)[k].w);                \
      *(ushort4*)(&As[b][row * 128 + (((c >> 1) ^ (row & 7)) << 3) + (c & 1) * 4]) = o; \
    }                                                          \
  }

  int tc = blockIdx.x;
  int tn = tc + nb;
  float4 gC[2], gN[2], gNN[2];
  LOADT(tc, gC);
  LOADT(tn, gN);
  STORET(0, gC);
  lds_barrier();
  int cur = 0;

  for (int it = 0; it < niter; ++it) {
    const int tnn = tn + nb;
    LOADT(tnn, gNN);
    STORET(cur ^ 1, gN);

    if (tc < NT) {
      f32x4 acc[4];
#pragma unroll
      for (int ntl = 0; ntl < 4; ++ntl) acc[ntl] = (f32x4){0.f, 0.f, 0.f, 0.f};

#pragma unroll
      for (int kk = 0; kk < 4; ++kk) {
        const int slot = (kk * 4 + lg) ^ (l15 & 7);
        int4 av = *(const int4*)(&As[cur][l15 * 128 + slot * 8]);
        const bf16x8 a = *reinterpret_cast<bf16x8*>(&av);
#pragma unroll
        for (int ntl = 0; ntl < 4; ++ntl)
          acc[ntl] = __builtin_amdgcn_mfma_f32_16x16x32_bf16(a, bfrag[ntl][kk], acc[ntl], 0, 0, 0);
      }

      const int n0 = tc * 16;
#pragma unroll
      for (int r = 0; r < 4; ++r) {
        float vals[4];
        float m = 1e-30f;
#pragma unroll
        for (int ntl = 0; ntl < 4; ++ntl) {
          const float x = acc[ntl][r] + b1r[ntl];
          vals[ntl] = x;
          m = fmaxf(m, fabsf(x));
        }
        m = fmaxf(m, __shfl_xor(m, 1));
        m = fmaxf(m, __shfl_xor(m, 2));
        m = fmaxf(m, __shfl_xor(m, 4));
        m = fmaxf(m, __shfl_xor(m, 8));
        const float inv = 127.0f * __builtin_amdgcn_rcpf(m);
        uint32_t pk = 0;
#pragma unroll
        for (int jj = 0; jj < 4; ++jj) {
          const int q = (int)rintf(vals[jj] * inv) + 128;       // 1..255
          pk |= (uint32_t)q << (8 * jj);
        }
        const int node = n0 + lg * 4 + r;
        if (node < Nn) {
          *(uint32_t*)(outp + (size_t)node * 128 + l15 * 8 + hw * 4) = pk;
          if (l15 == 0) outs[node * 2 + hw] = m * (1.0f / 127.0f);
        }
      }
    }

    lds_barrier();
    tc = tn; tn = tnn;
    gN[0] = gNN[0]; gN[1] = gNN[1];
    cur ^= 1;
  }
#undef LOADT
#undef STORET
}

// ---------------- Kernel 3: sharded edge scoring, XCD-verified via s_getreg ----------------
// Each wave reads its physical XCC id and drains bucket b=xcc via atomic cursor (u-slice
// 1.6 MB L2-local by construction), then steals from other buckets, then the ovf list.
__global__ __launch_bounds__(256, 8) void edge_score_shard(
    const uint8_t* __restrict__ u8, const uint8_t* __restrict__ v8,
    const float* __restrict__ su, const float* __restrict__ sv,  // [Nn][2]
    const int4* __restrict__ bkt, const int4* __restrict__ ovf,
    int* __restrict__ gmeta,
    const float* __restrict__ w2, const float* __restrict__ b2p,
    float* __restrict__ out)
{
  const int t  = threadIdx.x;
  const int l  = t & 63;
  const int q  = l & 15;
  const int lg = l >> 4;

  float w2r[8];
#pragma unroll
  for (int j = 0; j < 8; ++j) w2r[j] = w2[j * 16 + q];
  const float b2 = b2p[0];

  const float2* su2 = (const float2*)su;
  const float2* sv2 = (const float2*)sv;

#define PROCESS16(P, CNT, BASE)                                              \
  {                                                                          \
    int ee[4]; bool ok[4];                                                   \
    uint2 ug[4], vg[4];                                                      \
    float2 ss[4], sd[4];                                                     \
    _Pragma("unroll")                                                        \
    for (int i = 0; i < 4; ++i) {                                            \
      const int idx = (BASE) + i * 4 + lg;                                   \
      ok[i] = idx < (CNT);                                                   \
      const int4 rec = (P)[ok[i] ? idx : (CNT) - 1];                         \
      const int s = rec.x, d = rec.y;                                        \
      ee[i] = rec.z;                                                         \
      ug[i] = *(const uint2*)(u8 + (size_t)s * 128 + q * 8);                 \
      vg[i] = *(const uint2*)(v8 + (size_t)d * 128 + q * 8);                 \
      ss[i] = su2[s];                                                        \
      sd[i] = sv2[d];                                                        \
    }                                                                        \
    _Pragma("unroll")                                                        \
    for (int i = 0; i < 4; ++i) {                                            \
      const uint32_t ux = ug[i].x, uy = ug[i].y;                             \
      const uint32_t vx = vg[i].x, vy = vg[i].y;                             \
      const float bse0 = -128.0f * (ss[i].x + sd[i].x);                      \
      const float bse1 = -128.0f * (ss[i].y + sd[i].y);                      \
      float acc = 0.f;                                                       \
      _Pragma("unroll")                                                      \
      for (int j = 0; j < 4; ++j) {                                          \
        const float cu = (float)((ux >> (8 * j)) & 0xffu);                   \
        const float cv = (float)((vx >> (8 * j)) & 0xffu);                   \
        float x = fmaf(cu, ss[i].x, fmaf(cv, sd[i].x, bse0));                \
        x = fmaxf(x, 0.f);                                                   \
        acc = fmaf(x, w2r[j], acc);                                          \
      }                                                                      \
      _Pragma("unroll")                                                      \
      for (int j = 0; j < 4; ++j) {                                          \
        const float cu = (float)((uy >> (8 * j)) & 0xffu);                   \
        const float cv = (float)((vy >> (8 * j)) & 0xffu);                   \
        float x = fmaf(cu, ss[i].y, fmaf(cv, sd[i].y, bse1));                \
        x = fmaxf(x, 0.f);                                                   \
        acc = fmaf(x, w2r[4 + j], acc);                                      \
      }                                                                      \
      acc += __shfl_xor(acc, 1);                                             \
      acc += __shfl_xor(acc, 2);                                             \
      acc += __shfl_xor(acc, 4);                                             \
      acc += __shfl_xor(acc, 8);                                             \
      if (q == 0 && ok[i]) out[ee[i]] = acc + b2;                            \
    }                                                                        \
  }

  int xcc;
  asm volatile("s_getreg_b32 %0, hwreg(20, 0, 32)" : "=s"(xcc));
  xcc &= 7;

  // own bucket first (L2-local u-slice), then steal
  for (int bb = 0; bb < 8; ++bb) {
    const int b  = (xcc + bb) & 7;
    int cnt = gmeta[b];
    cnt = cnt < BCAP ? cnt : BCAP;
    if (cnt <= 0) continue;
    const int4* p = bkt + (size_t)b * BCAP;
    while (true) {
      int c = 0;
      if (l == 0) c = atomicAdd(&gmeta[9 + b], 1);
      c = __shfl(c, 0);
      const int base = c * 16;
      if (base >= cnt) break;
      PROCESS16(p, cnt, base)
    }
  }
  // overflow list (empty in practice)
  {
    const int ocnt = gmeta[8];
    if (ocnt > 0) {
      while (true) {
        int c = 0;
        if (l == 0) c = atomicAdd(&gmeta[17], 1);
        c = __shfl(c, 0);
        const int base = c * 16;
        if (base >= ocnt) break;
        PROCESS16(ovf, ocnt, base)
      }
    }
  }
#undef PROCESS16
}

extern "C" void kernel_launch(void* const* d_in, const int* in_sizes, int n_in,
                              void* d_out, int out_size, void* d_ws, size_t ws_size,
                              hipStream_t stream) {
  const float* h   = (const float*)d_in[0];
  const int*   src = (const int*)d_in[1];
  const int*   dst = (const int*)d_in[2];
  const float* W1  = (const float*)d_in[3];
  const float* b1  = (const float*)d_in[4];
  const float* w2  = (const float*)d_in[5];
  const float* b2  = (const float*)d_in[6];
  float* out = (float*)d_out;

  const int nh = in_sizes[0];
  const int Nn = nh / 128;
  const int E  = in_sizes[1];

  uint8_t* ws = (uint8_t*)d_ws;
  int4*  blob = (int4*)ws;                                          // 64 KiB
  size_t off  = 65536;
  int*  gmeta = (int*)(ws + off);    off += 512;
  float* su   = (float*)(ws + off);  off += (size_t)Nn * 8;
  off = (off + 511) & ~(size_t)511;
  float* sv   = (float*)(ws + off);  off += (size_t)Nn * 8;
  off = (off + 511) & ~(size_t)511;
  uint8_t* u8 = ws + off;            off += (size_t)Nn * 128;
  uint8_t* v8 = ws + off;            off += (size_t)Nn * 128;
  off = (off + 511) & ~(size_t)511;
  int4*  bkt  = (int4*)(ws + off);   off += (size_t)8 * BCAP * 16;  // 12.6 MB
  int4*  ovfl = (int4*)(ws + off);   // E * 16 B

  // shard divisor: magic for div = ceil(Nn/8)
  const unsigned div  = (unsigned)((Nn + 7) / 8);
  const unsigned Mdiv = (unsigned)((((unsigned long long)1 << 34) + div - 1) / div);

  hipMemsetAsync(gmeta, 0, 128, stream);

  hipLaunchKernelGGL(repack_bucket, dim3(272), dim3(256), 0, stream,
                     W1, blob, src, dst, bkt, ovfl, gmeta, E, Mdiv);

  const int NT      = (Nn + 15) / 16;
  const int nblocks = 768;
  const int niter   = (NT + nblocks - 1) / nblocks;
  hipLaunchKernelGGL(node_uv, dim3(nblocks), dim3(256), 0, stream,
                     h, blob, b1, u8, v8, su, sv, Nn, NT, nblocks, niter);

  hipLaunchKernelGGL(edge_score_shard, dim3(2048), dim3(256), 0, stream,
                     u8, v8, su, sv, bkt, ovfl, gmeta, w2, b2, out);
}

// Round 13
// 80.124 us; speedup vs baseline: 32.1433x; 32.1433x over previous
//
#include <hip/hip_runtime.h>
#include <hip/hip_bf16.h>
#include <stdint.h>

typedef short bf16x8 __attribute__((ext_vector_type(8)));
typedef float f32x4  __attribute__((ext_vector_type(4)));

__device__ __forceinline__ ushort f2b(float f) {
  __hip_bfloat16 t = __float2bfloat16(f);
  return *reinterpret_cast<ushort*>(&t);
}
__device__ __forceinline__ bf16x8 pack8(float4 a, float4 b) {
  bf16x8 r;
  r[0]=(short)f2b(a.x); r[1]=(short)f2b(a.y); r[2]=(short)f2b(a.z); r[3]=(short)f2b(a.w);
  r[4]=(short)f2b(b.x); r[5]=(short)f2b(b.y); r[6]=(short)f2b(b.z); r[7]=(short)f2b(b.w);
  return r;
}

// Raw barrier: LDS-visibility only; global prefetch loads stay in flight (T4).
__device__ __forceinline__ void lds_barrier() {
  asm volatile("s_waitcnt lgkmcnt(0)" ::: "memory");
  __builtin_amdgcn_sched_barrier(0);
  __builtin_amdgcn_s_barrier();
  __builtin_amdgcn_sched_barrier(0);
}

#define BCAP 98304   // per-bucket capacity (mean 75k, sd ~256 under multinomial)

// ---------------- Kernel 1: edge bucketing (blocks <1024) + W1 repack (blocks >=1024) -------
// gmeta: [0..7] bucket counts, [8] ovf count. Records are int4 {s, d, e, 0}.
__global__ void repack_bucket(const float* __restrict__ W1, int4* __restrict__ blob,
                              const int* __restrict__ src, const int* __restrict__ dst,
                              int4* __restrict__ bkt, int4* __restrict__ ovf,
                              int* __restrict__ gmeta, int E, unsigned Mdiv) {
  const int bid = blockIdx.x;
  const int t0  = threadIdx.x;
  if (bid >= 1024) {
    const int tid = (bid - 1024) * 256 + t0;          // 0..4095
    const int l15  = tid & 15;
    const int lg   = (tid >> 4) & 3;
    const int kk   = (tid >> 6) & 3;
    const int nt   = (tid >> 8) & 7;
    const int half = (tid >> 11) & 1;
    const float* wp = W1 + (size_t)(nt * 16 + l15) * 256 + half * 128 + kk * 32 + lg * 8;
    const float4 fa = *(const float4*)wp;
    const float4 fb = *(const float4*)(wp + 4);
    bf16x8 r = pack8(fa, fb);
    blob[tid] = *reinterpret_cast<int4*>(&r);
    return;
  }
  // ---- bucket path: per-block histogram -> one global reserve per bucket -> scatter ----
  __shared__ int lh[8], lh2[8], lbs[8];
  const int C  = (E + 1023) >> 10;
  const int e0 = bid * C;
  const int e1 = (e0 + C) < E ? (e0 + C) : E;
  if (t0 < 8) { lh[t0] = 0; lh2[t0] = 0; }
  __syncthreads();
  for (int e = e0 + t0; e < e1; e += 256) {
    const unsigned s = (unsigned)src[e];
    int sh = (int)(((unsigned long long)s * Mdiv) >> 34);
    sh = sh > 7 ? 7 : sh;
    atomicAdd(&lh[sh], 1);
  }
  __syncthreads();
  if (t0 < 8) lbs[t0] = atomicAdd(&gmeta[t0], lh[t0]);
  __syncthreads();
  for (int e = e0 + t0; e < e1; e += 256) {
    const int s = src[e];
    const int d = dst[e];
    int sh = (int)(((unsigned long long)(unsigned)s * Mdiv) >> 34);
    sh = sh > 7 ? 7 : sh;
    const int r = atomicAdd(&lh2[sh], 1);
    const int slot = lbs[sh] + r;
    const int4 rec = make_int4(s, d, e, 0);
    if (slot < BCAP) bkt[(size_t)sh * BCAP + slot] = rec;
    else             ovf[atomicAdd(&gmeta[8], 1)] = rec;
  }
}

// ---------------- Kernel 2: node u/v -> biased uint8 + per-half scales (round-8 exact) ------
__global__ __launch_bounds__(256, 3) void node_uv(
    const float* __restrict__ h, const int4* __restrict__ blob,
    const float* __restrict__ b1,
    uint8_t* __restrict__ u8, uint8_t* __restrict__ v8,
    float* __restrict__ su, float* __restrict__ sv,   // [Nn][2]
    int Nn, int NT, int nb, int niter)
{
  __shared__ ushort As[2][2048];

  const int t0   = threadIdx.x;
  const int w    = t0 >> 6;
  const int l    = t0 & 63;
  const int l15  = l & 15;
  const int lg   = l >> 4;
  const int half = w >> 1;
  const int hw   = w & 1;

  bf16x8 bfrag[4][4];
#pragma unroll
  for (int ntl = 0; ntl < 4; ++ntl)
#pragma unroll
    for (int kk = 0; kk < 4; ++kk) {
      int4 x = blob[((half * 8 + hw * 4 + ntl) * 4 + kk) * 64 + l];
      bfrag[ntl][kk] = *reinterpret_cast<bf16x8*>(&x);
    }

  float b1r[4];
#pragma unroll
  for (int ntl = 0; ntl < 4; ++ntl)
    b1r[ntl] = half ? 0.f : b1[hw * 64 + ntl * 16 + l15];

  uint8_t* __restrict__ outp = half ? v8 : u8;
  float*   __restrict__ outs = half ? sv : su;

  const float4* h4 = (const float4*)h;

#define LOADT(T, g)                                            \
  {                                                            \
    const size_t hb = (size_t)(T) * 512;                       \
    _Pragma("unroll")                                          \
    for (int k = 0; k < 2; ++k) {                              \
      const int i = k * 256 + t0;                              \
      const int gr = (T) * 16 + (i >> 5);                      \
      (g)[k] = h4[gr < Nn ? hb + i : 0];                       \
    }                                                          \
  }

#define STORET(b, g)                                           \
  {                                                            \
    _Pragma("unroll")                                          \
    for (int k = 0; k < 2; ++k) {                              \
      const int i = k * 256 + t0, row = i >> 5, c = i & 31;    \
      ushort4 o;                                               \
      o.x = f2b((g)[k].x); o.y = f2b((g)[k].y);                \
      o.z = f2b((g)[k].z); o.w = f2b((g)[k].w);                \
      *(ushort4*)(&As[b][row * 128 + (((c >> 1) ^ (row & 7)) << 3) + (c & 1) * 4]) = o; \
    }                                                          \
  }

  int tc = blockIdx.x;
  int tn = tc + nb;
  float4 gC[2], gN[2], gNN[2];
  LOADT(tc, gC);
  LOADT(tn, gN);
  STORET(0, gC);
  lds_barrier();
  int cur = 0;

  for (int it = 0; it < niter; ++it) {
    const int tnn = tn + nb;
    LOADT(tnn, gNN);
    STORET(cur ^ 1, gN);

    if (tc < NT) {
      f32x4 acc[4];
#pragma unroll
      for (int ntl = 0; ntl < 4; ++ntl) acc[ntl] = (f32x4){0.f, 0.f, 0.f, 0.f};

#pragma unroll
      for (int kk = 0; kk < 4; ++kk) {
        const int slot = (kk * 4 + lg) ^ (l15 & 7);
        int4 av = *(const int4*)(&As[cur][l15 * 128 + slot * 8]);
        const bf16x8 a = *reinterpret_cast<bf16x8*>(&av);
#pragma unroll
        for (int ntl = 0; ntl < 4; ++ntl)
          acc[ntl] = __builtin_amdgcn_mfma_f32_16x16x32_bf16(a, bfrag[ntl][kk], acc[ntl], 0, 0, 0);
      }

      const int n0 = tc * 16;
#pragma unroll
      for (int r = 0; r < 4; ++r) {
        float vals[4];
        float m = 1e-30f;
#pragma unroll
        for (int ntl = 0; ntl < 4; ++ntl) {
          const float x = acc[ntl][r] + b1r[ntl];
          vals[ntl] = x;
          m = fmaxf(m, fabsf(x));
        }
        m = fmaxf(m, __shfl_xor(m, 1));
        m = fmaxf(m, __shfl_xor(m, 2));
        m = fmaxf(m, __shfl_xor(m, 4));
        m = fmaxf(m, __shfl_xor(m, 8));
        const float inv = 127.0f * __builtin_amdgcn_rcpf(m);
        uint32_t pk = 0;
#pragma unroll
        for (int jj = 0; jj < 4; ++jj) {
          const int q = (int)rintf(vals[jj] * inv) + 128;       // 1..255
          pk |= (uint32_t)q << (8 * jj);
        }
        const int node = n0 + lg * 4 + r;
        if (node < Nn) {
          *(uint32_t*)(outp + (size_t)node * 128 + l15 * 8 + hw * 4) = pk;
          if (l15 == 0) outs[node * 2 + hw] = m * (1.0f / 127.0f);
        }
      }
    }

    lds_barrier();
    tc = tn; tn = tnn;
    gN[0] = gNN[0]; gN[1] = gNN[1];
    cur ^= 1;
  }
#undef LOADT
#undef STORET
}

// ---------------- Kernel 3: sharded edge scoring, STATIC partition (no atomics) -------------
// Block bid serves bucket bid&7 (T1 bid->XCD round-robin heuristic), contiguous slice
// bid>>3 of NBJ. 16-lane group per edge, 4 edges per group-iteration, int4 records.
__global__ __launch_bounds__(256) void edge_score_shard(
    const uint8_t* __restrict__ u8, const uint8_t* __restrict__ v8,
    const float* __restrict__ su, const float* __restrict__ sv,  // [Nn][2]
    const int4* __restrict__ bkt, const int4* __restrict__ ovf,
    const int* __restrict__ gmeta,
    const float* __restrict__ w2, const float* __restrict__ b2p,
    float* __restrict__ out)
{
  const int t  = threadIdx.x;
  const int l  = t & 63;
  const int q  = l & 15;
  const int lg = l >> 4;
  const int w  = t >> 6;

  float w2r[8];
#pragma unroll
  for (int j = 0; j < 8; ++j) w2r[j] = w2[j * 16 + q];
  const float b2 = b2p[0];

  const float2* su2 = (const float2*)su;
  const float2* sv2 = (const float2*)sv;

#define EDGELOOP(P, LO, HI)                                                  \
  for (int base = (LO) + w * 16; base < (HI); base += 64) {                  \
    int ee[4]; bool ok[4];                                                   \
    uint2 ug[4], vg[4];                                                      \
    float2 ss[4], sd[4];                                                     \
    _Pragma("unroll")                                                        \
    for (int i = 0; i < 4; ++i) {                                            \
      const int idx = base + i * 4 + lg;                                     \
      ok[i] = idx < (HI);                                                    \
      const int4 rec = (P)[ok[i] ? idx : (HI) - 1];                          \
      const int s = rec.x, d = rec.y;                                        \
      ee[i] = rec.z;                                                         \
      ug[i] = *(const uint2*)(u8 + (size_t)s * 128 + q * 8);                 \
      vg[i] = *(const uint2*)(v8 + (size_t)d * 128 + q * 8);                 \
      ss[i] = su2[s];                                                        \
      sd[i] = sv2[d];                                                        \
    }                                                                        \
    _Pragma("unroll")                                                        \
    for (int i = 0; i < 4; ++i) {                                            \
      const uint32_t ux = ug[i].x, uy = ug[i].y;                             \
      const uint32_t vx = vg[i].x, vy = vg[i].y;                             \
      const float bse0 = -128.0f * (ss[i].x + sd[i].x);                      \
      const float bse1 = -128.0f * (ss[i].y + sd[i].y);                      \
      float acc = 0.f;                                                       \
      _Pragma("unroll")                                                      \
      for (int j = 0; j < 4; ++j) {                                          \
        const float cu = (float)((ux >> (8 * j)) & 0xffu);                   \
        const float cv = (float)((vx >> (8 * j)) & 0xffu);                   \
        float x = fmaf(cu, ss[i].x, fmaf(cv, sd[i].x, bse0));                \
        x = fmaxf(x, 0.f);                                                   \
        acc = fmaf(x, w2r[j], acc);                                          \
      }                                                                      \
      _Pragma("unroll")                                                      \
      for (int j = 0; j < 4; ++j) {                                          \
        const float cu = (float)((uy >> (8 * j)) & 0xffu);                   \
        const float cv = (float)((vy >> (8 * j)) & 0xffu);                   \
        float x = fmaf(cu, ss[i].y, fmaf(cv, sd[i].y, bse1));                \
        x = fmaxf(x, 0.f);                                                   \
        acc = fmaf(x, w2r[4 + j], acc);                                      \
      }                                                                      \
      acc += __shfl_xor(acc, 1);                                             \
      acc += __shfl_xor(acc, 2);                                             \
      acc += __shfl_xor(acc, 4);                                             \
      acc += __shfl_xor(acc, 8);                                             \
      if (q == 0 && ok[i]) out[ee[i]] = acc + b2;                            \
    }                                                                        \
  }

  {
    const int b   = blockIdx.x & 7;
    const int j   = blockIdx.x >> 3;
    const int NBJ = gridDim.x >> 3;
    int cnt = gmeta[b];
    cnt = cnt < BCAP ? cnt : BCAP;
    if (cnt > 0) {
      const int4* p = bkt + (size_t)b * BCAP;
      const int lo = (int)((long long)cnt * j / NBJ);
      const int hi = (int)((long long)cnt * (j + 1) / NBJ);
      EDGELOOP(p, lo, hi)
    }
  }
  {
    const int ocnt = gmeta[8];
    if (ocnt > 0) {
      const int NB = gridDim.x;
      const int lo = (int)((long long)ocnt * blockIdx.x / NB);
      const int hi = (int)((long long)ocnt * (blockIdx.x + 1) / NB);
      EDGELOOP(ovf, lo, hi)
    }
  }
#undef EDGELOOP
}

extern "C" void kernel_launch(void* const* d_in, const int* in_sizes, int n_in,
                              void* d_out, int out_size, void* d_ws, size_t ws_size,
                              hipStream_t stream) {
  const float* h   = (const float*)d_in[0];
  const int*   src = (const int*)d_in[1];
  const int*   dst = (const int*)d_in[2];
  const float* W1  = (const float*)d_in[3];
  const float* b1  = (const float*)d_in[4];
  const float* w2  = (const float*)d_in[5];
  const float* b2  = (const float*)d_in[6];
  float* out = (float*)d_out;

  const int nh = in_sizes[0];
  const int Nn = nh / 128;
  const int E  = in_sizes[1];

  uint8_t* ws = (uint8_t*)d_ws;
  int4*  blob = (int4*)ws;                                          // 64 KiB
  size_t off  = 65536;
  int*  gmeta = (int*)(ws + off);    off += 512;
  float* su   = (float*)(ws + off);  off += (size_t)Nn * 8;
  off = (off + 511) & ~(size_t)511;
  float* sv   = (float*)(ws + off);  off += (size_t)Nn * 8;
  off = (off + 511) & ~(size_t)511;
  uint8_t* u8 = ws + off;            off += (size_t)Nn * 128;
  uint8_t* v8 = ws + off;            off += (size_t)Nn * 128;
  off = (off + 511) & ~(size_t)511;
  int4*  bkt  = (int4*)(ws + off);   off += (size_t)8 * BCAP * 16;  // 12.6 MB
  int4*  ovfl = (int4*)(ws + off);   // E * 16 B

  // shard divisor: magic for div = ceil(Nn/8)
  const unsigned div  = (unsigned)((Nn + 7) / 8);
  const unsigned Mdiv = (unsigned)((((unsigned long long)1 << 34) + div - 1) / div);

  hipMemsetAsync(gmeta, 0, 128, stream);

  hipLaunchKernelGGL(repack_bucket, dim3(1040), dim3(256), 0, stream,
                     W1, blob, src, dst, bkt, ovfl, gmeta, E, Mdiv);

  const int NT      = (Nn + 15) / 16;
  const int nblocks = 768;
  const int niter   = (NT + nblocks - 1) / nblocks;
  hipLaunchKernelGGL(node_uv, dim3(nblocks), dim3(256), 0, stream,
                     h, blob, b1, u8, v8, su, sv, Nn, NT, nblocks, niter);

  hipLaunchKernelGGL(edge_score_shard, dim3(2048), dim3(256), 0, stream,
                     u8, v8, su, sv, bkt, ovfl, gmeta, w2, b2, out);
}

// Round 14
// 59.381 us; speedup vs baseline: 43.3714x; 1.3493x over previous
//
#include <hip/hip_runtime.h>
#include <hip/hip_bf16.h>
#include <stdint.h>

typedef short bf16x8 __attribute__((ext_vector_type(8)));
typedef float f32x4  __attribute__((ext_vector_type(4)));
typedef float f32x2  __attribute__((ext_vector_type(2)));

__device__ __forceinline__ ushort f2b(float f) {
  __hip_bfloat16 t = __float2bfloat16(f);
  return *reinterpret_cast<ushort*>(&t);
}
__device__ __forceinline__ bf16x8 pack8(float4 a, float4 b) {
  bf16x8 r;
  r[0]=(short)f2b(a.x); r[1]=(short)f2b(a.y); r[2]=(short)f2b(a.z); r[3]=(short)f2b(a.w);
  r[4]=(short)f2b(b.x); r[5]=(short)f2b(b.y); r[6]=(short)f2b(b.z); r[7]=(short)f2b(b.w);
  return r;
}

// Raw barrier: LDS-visibility only; global prefetch loads stay in flight (T4).
__device__ __forceinline__ void lds_barrier() {
  asm volatile("s_waitcnt lgkmcnt(0)" ::: "memory");
  __builtin_amdgcn_sched_barrier(0);
  __builtin_amdgcn_s_barrier();
  __builtin_amdgcn_sched_barrier(0);
}

// ---------------- Phase 0: repack W1 -> bf16 B-fragment blob ----------------
__global__ void repack_W1(const float* __restrict__ W1, int4* __restrict__ blob) {
  const int tid = blockIdx.x * 256 + threadIdx.x;     // 0..4095
  const int l15  = tid & 15;
  const int lg   = (tid >> 4) & 3;
  const int kk   = (tid >> 6) & 3;
  const int nt   = (tid >> 8) & 7;
  const int half = (tid >> 11) & 1;
  const float* wp = W1 + (size_t)(nt * 16 + l15) * 256 + half * 128 + kk * 32 + lg * 8;
  const float4 fa = *(const float4*)wp;
  const float4 fb = *(const float4*)(wp + 4);
  bf16x8 r = pack8(fa, fb);
  blob[tid] = *reinterpret_cast<int4*>(&r);
}

// ---------------- Phase 1: u/v -> biased uint8 + per-half scales (round-8 exact) ------------
__global__ __launch_bounds__(256, 3) void node_uv(
    const float* __restrict__ h, const int4* __restrict__ blob,
    const float* __restrict__ b1,
    uint8_t* __restrict__ u8, uint8_t* __restrict__ v8,
    float* __restrict__ su, float* __restrict__ sv,   // [Nn][2]
    int Nn, int NT, int nb, int niter)
{
  __shared__ ushort As[2][2048];

  const int t0   = threadIdx.x;
  const int w    = t0 >> 6;
  const int l    = t0 & 63;
  const int l15  = l & 15;
  const int lg   = l >> 4;
  const int half = w >> 1;
  const int hw   = w & 1;

  bf16x8 bfrag[4][4];
#pragma unroll
  for (int ntl = 0; ntl < 4; ++ntl)
#pragma unroll
    for (int kk = 0; kk < 4; ++kk) {
      int4 x = blob[((half * 8 + hw * 4 + ntl) * 4 + kk) * 64 + l];
      bfrag[ntl][kk] = *reinterpret_cast<bf16x8*>(&x);
    }

  float b1r[4];
#pragma unroll
  for (int ntl = 0; ntl < 4; ++ntl)
    b1r[ntl] = half ? 0.f : b1[hw * 64 + ntl * 16 + l15];

  uint8_t* __restrict__ outp = half ? v8 : u8;
  float*   __restrict__ outs = half ? sv : su;

  const float4* h4 = (const float4*)h;

#define LOADT(T, g)                                            \
  {                                                            \
    const size_t hb = (size_t)(T) * 512;                       \
    _Pragma("unroll")                                          \
    for (int k = 0; k < 2; ++k) {                              \
      const int i = k * 256 + t0;                              \
      const int gr = (T) * 16 + (i >> 5);                      \
      (g)[k] = h4[gr < Nn ? hb + i : 0];                       \
    }                                                          \
  }

#define STORET(b, g)                                           \
  {                                                            \
    _Pragma("unroll")                                          \
    for (int k = 0; k < 2; ++k) {                              \
      const int i = k * 256 + t0, row = i >> 5, c = i & 31;    \
      ushort4 o;                                               \
      o.x = f2b((g)[k].x); o.y = f2b((g)[k].y);                \
      o.z = f2b((g)[k].z); o.w = f2b((g)[k].w);                \
      *(ushort4*)(&As[b][row * 128 + (((c >> 1) ^ (row & 7)) << 3) + (c & 1) * 4]) = o; \
    }                                                          \
  }

  int tc = blockIdx.x;
  int tn = tc + nb;
  float4 gC[2], gN[2], gNN[2];
  LOADT(tc, gC);
  LOADT(tn, gN);
  STORET(0, gC);
  lds_barrier();
  int cur = 0;

  for (int it = 0; it < niter; ++it) {
    const int tnn = tn + nb;
    LOADT(tnn, gNN);          // 2-ahead; stays in flight across the raw barrier
    STORET(cur ^ 1, gN);      // compiler waits counted vmcnt for gN only

    if (tc < NT) {
      f32x4 acc[4];
#pragma unroll
      for (int ntl = 0; ntl < 4; ++ntl) acc[ntl] = (f32x4){0.f, 0.f, 0.f, 0.f};

#pragma unroll
      for (int kk = 0; kk < 4; ++kk) {
        const int slot = (kk * 4 + lg) ^ (l15 & 7);
        int4 av = *(const int4*)(&As[cur][l15 * 128 + slot * 8]);
        const bf16x8 a = *reinterpret_cast<bf16x8*>(&av);
#pragma unroll
        for (int ntl = 0; ntl < 4; ++ntl)
          acc[ntl] = __builtin_amdgcn_mfma_f32_16x16x32_bf16(a, bfrag[ntl][kk], acc[ntl], 0, 0, 0);
      }

      const int n0 = tc * 16;
#pragma unroll
      for (int r = 0; r < 4; ++r) {
        float vals[4];
        float m = 1e-30f;
#pragma unroll
        for (int ntl = 0; ntl < 4; ++ntl) {
          const float x = acc[ntl][r] + b1r[ntl];
          vals[ntl] = x;
          m = fmaxf(m, fabsf(x));
        }
        m = fmaxf(m, __shfl_xor(m, 1));
        m = fmaxf(m, __shfl_xor(m, 2));
        m = fmaxf(m, __shfl_xor(m, 4));
        m = fmaxf(m, __shfl_xor(m, 8));
        const float inv = 127.0f * __builtin_amdgcn_rcpf(m);
        uint32_t pk = 0;
#pragma unroll
        for (int jj = 0; jj < 4; ++jj) {
          const int q = (int)rintf(vals[jj] * inv) + 128;       // 1..255
          pk |= (uint32_t)q << (8 * jj);
        }
        const int node = n0 + lg * 4 + r;
        if (node < Nn) {
          *(uint32_t*)(outp + (size_t)node * 128 + l15 * 8 + hw * 4) = pk;
          if (l15 == 0) outs[node * 2 + hw] = m * (1.0f / 127.0f);
        }
      }
    }

    lds_barrier();
    tc = tn; tn = tnn;
    gN[0] = gNN[0]; gN[1] = gNN[1];
    cur ^= 1;
  }
#undef LOADT
#undef STORET
}

// ---------------- Phase 2: score via packed-f32 decode ------------------------------------
// 16-lane group per edge, 4 edges per group-iteration. Lane q reads bytes = cols {j*16+q};
// j<4 -> scale .x, j>=4 -> .y. Decode math on f32x2 -> v_pk_fma_f32 / v_pk_max_f32.
__global__ __launch_bounds__(256) void edge_score_i8(
    const uint8_t* __restrict__ u8, const uint8_t* __restrict__ v8,
    const float* __restrict__ su, const float* __restrict__ sv,  // [Nn][2]
    const int* __restrict__ src, const int* __restrict__ dst,
    const float* __restrict__ w2, const float* __restrict__ b2p,
    float* __restrict__ out, int E)
{
  const int t  = threadIdx.x;
  const int l  = t & 63;
  const int q  = l & 15;
  const int lg = l >> 4;

  f32x2 w2p[4];
#pragma unroll
  for (int j2 = 0; j2 < 4; ++j2) {
    w2p[j2][0] = w2[(2 * j2    ) * 16 + q];
    w2p[j2][1] = w2[(2 * j2 + 1) * 16 + q];
  }
  const float b2 = b2p[0];
  const f32x2 zero2 = {0.f, 0.f};

  const int gw = blockIdx.x * 4 + (t >> 6);
  const int TW = gridDim.x * 4;
  const float2* su2 = (const float2*)su;
  const float2* sv2 = (const float2*)sv;

  for (int base = gw * 16; base < E; base += TW * 16) {
    int e[4]; bool ok[4];
    uint2 ug[4], vg[4];
    float2 ss[4], sd[4];
#pragma unroll
    for (int i = 0; i < 4; ++i) {
      e[i]  = base + i * 4 + lg;
      ok[i] = e[i] < E;
      const int eS = ok[i] ? e[i] : 0;
      const int s = src[eS];
      const int d = dst[eS];
      ug[i] = *(const uint2*)(u8 + (size_t)s * 128 + q * 8);
      vg[i] = *(const uint2*)(v8 + (size_t)d * 128 + q * 8);
      ss[i] = su2[s];
      sd[i] = sv2[d];
    }
#pragma unroll
    for (int i = 0; i < 4; ++i) {
      const uint32_t ux = ug[i].x, uy = ug[i].y;
      const uint32_t vx = vg[i].x, vy = vg[i].y;
      const f32x2 ssx = {ss[i].x, ss[i].x}, sdx = {sd[i].x, sd[i].x};
      const f32x2 ssy = {ss[i].y, ss[i].y}, sdy = {sd[i].y, sd[i].y};
      const float b0 = -128.0f * (ss[i].x + sd[i].x);
      const float b1e = -128.0f * (ss[i].y + sd[i].y);
      const f32x2 bse0 = {b0, b0}, bse1 = {b1e, b1e};
      f32x2 acc2 = {0.f, 0.f};

      // bytes 0,1 / 2,3 of low word (scale .x)
      {
        f32x2 cu = { (float)( ux        & 0xffu), (float)((ux >>  8) & 0xffu) };
        f32x2 cv = { (float)( vx        & 0xffu), (float)((vx >>  8) & 0xffu) };
        f32x2 x = cu * ssx + (cv * sdx + bse0);
        x = __builtin_elementwise_max(x, zero2);
        acc2 = x * w2p[0] + acc2;
      }
      {
        f32x2 cu = { (float)((ux >> 16) & 0xffu), (float)((ux >> 24) & 0xffu) };
        f32x2 cv = { (float)((vx >> 16) & 0xffu), (float)((vx >> 24) & 0xffu) };
        f32x2 x = cu * ssx + (cv * sdx + bse0);
        x = __builtin_elementwise_max(x, zero2);
        acc2 = x * w2p[1] + acc2;
      }
      // bytes 0,1 / 2,3 of high word (scale .y)
      {
        f32x2 cu = { (float)( uy        & 0xffu), (float)((uy >>  8) & 0xffu) };
        f32x2 cv = { (float)( vy        & 0xffu), (float)((vy >>  8) & 0xffu) };
        f32x2 x = cu * ssy + (cv * sdy + bse1);
        x = __builtin_elementwise_max(x, zero2);
        acc2 = x * w2p[2] + acc2;
      }
      {
        f32x2 cu = { (float)((uy >> 16) & 0xffu), (float)((uy >> 24) & 0xffu) };
        f32x2 cv = { (float)((vy >> 16) & 0xffu), (float)((vy >> 24) & 0xffu) };
        f32x2 x = cu * ssy + (cv * sdy + bse1);
        x = __builtin_elementwise_max(x, zero2);
        acc2 = x * w2p[3] + acc2;
      }

      float acc = acc2[0] + acc2[1];
      acc += __shfl_xor(acc, 1);
      acc += __shfl_xor(acc, 2);
      acc += __shfl_xor(acc, 4);
      acc += __shfl_xor(acc, 8);
      if (q == 0 && ok[i]) out[e[i]] = acc + b2;
    }
  }
}

extern "C" void kernel_launch(void* const* d_in, const int* in_sizes, int n_in,
                              void* d_out, int out_size, void* d_ws, size_t ws_size,
                              hipStream_t stream) {
  const float* h   = (const float*)d_in[0];
  const int*   src = (const int*)d_in[1];
  const int*   dst = (const int*)d_in[2];
  const float* W1  = (const float*)d_in[3];
  const float* b1  = (const float*)d_in[4];
  const float* w2  = (const float*)d_in[5];
  const float* b2  = (const float*)d_in[6];
  float* out = (float*)d_out;

  const int nh = in_sizes[0];
  const int Nn = nh / 128;
  const int E  = in_sizes[1];

  uint8_t* ws = (uint8_t*)d_ws;
  int4*  blob = (int4*)ws;                                          // 64 KiB
  size_t off  = 65536;
  float* su   = (float*)(ws + off);  off += (size_t)Nn * 8;
  off = (off + 511) & ~(size_t)511;
  float* sv   = (float*)(ws + off);  off += (size_t)Nn * 8;
  off = (off + 511) & ~(size_t)511;
  uint8_t* u8 = ws + off;            off += (size_t)Nn * 128;
  uint8_t* v8 = ws + off;

  hipLaunchKernelGGL(repack_W1, dim3(16), dim3(256), 0, stream, W1, blob);

  const int NT      = (Nn + 15) / 16;
  const int nblocks = 768;
  const int niter   = (NT + nblocks - 1) / nblocks;
  hipLaunchKernelGGL(node_uv, dim3(nblocks), dim3(256), 0, stream,
                     h, blob, b1, u8, v8, su, sv, Nn, NT, nblocks, niter);

  hipLaunchKernelGGL(edge_score_i8, dim3(3072), dim3(256), 0, stream,
                     u8, v8, su, sv, src, dst, w2, b2, out, E);
}